// Round 10
// baseline (841.293 us; speedup 1.0000x reference)
//
#include <hip/hip_runtime.h>
#include <stdint.h>

// CAN_Layer reduces exactly to: out[:, :2048] = out[:, 2048:] =
//   0.5 * (protein @ Wv_p + drug @ Wv_d)
// (seq-len 1 -> softmax over singleton axis == 1 -> attention = identity on V).
//
// Pipeline:
//   Pass 1a: cast+transpose Wv_p/Wv_d -> Wt bf16 [2048][4096] (B^T layout).
//   Pass 1b: cast protein|drug -> Abf bf16 [16384][4096].
//   Pass 2:  gemm8 — 256x256 tile, BK=64, 8 waves (2x4), R8's whole-tile
//            weave (best verified: 303us, MfmaUtil 39.5%), with B taken OFF
//            the LDS pipe: bR fragments load directly from global (L2-resident
//            2MB stripe) in the same in-place WAR refill slots. LDS per tile:
//            reads 2304->1536 cyc, writes halved -> LDS pipe (was ~2560 cyc
//            ~ at the 2483-cyc MFMA wall) now well under it. LDS 128->64KB.
//            Tile-end wait: counted VMW(8) (retires the 4 A-stage glls;
//            next-tile B register loads stay in flight, compiler-waited).
//
// Ledger (tile t, buf b=t&1, per-THREAD VMEM order):
//   [1-4] stage_a S_A(t+2)->buf b | weave: MFMA(t) + in-place aR refill
//   R_A(t+1)<-As[nb] (lgkm) + in-place bR refill B(t+1)<-global [5-12] |
//   VMW(8) retires #1-4 = S_A(t+2) | LGW0 drains R_A(t+1) | BAR.
//   Overwrite: S_A(t+2)->buf b issued after BAR(t-1) which followed every
//   wave's LGW0 covering R_A(t) reads of buf b. Staged-data visibility:
//   R_A(t+2) (during t+1) follows BAR(t) which followed every wave's VMW(8).
//   B(t+1) regs: first use at t+1 weave start; compiler inserts the vmcnt
//   wait (register dataflow); issue->use cover ~1500cyc >> L2 ~200cyc.
//   Prologue: S_A(0),S_A(1) (8 gll) + B(0) direct loads (8); VMW(8) retires
//   both A stages; BAR; read aR(0); LGW0; BAR  <- seam fence (R8 lesson).
//   Tail: t=61 stages S_A(63), retired by t=61's VMW(8); tile 62 body
//   refills R_A(63)<-buf1 + B(63) global; tile 63 MFMA-only, barrier-free.

typedef __attribute__((ext_vector_type(8))) short short8;
typedef __attribute__((ext_vector_type(4))) float float4v;
typedef __attribute__((ext_vector_type(2))) unsigned int uint2v;

typedef const __attribute__((address_space(1))) unsigned int* gp_t;
typedef __attribute__((address_space(3))) unsigned int* lp_t;

#define M_DIM 16384
#define N_DIM 2048
#define K_DIM 4096
#define OUT_LD 4096

static __device__ __forceinline__ unsigned int pack_bf16x2(float x, float y) {
  union { float f; unsigned int u; } a, b;
  a.f = x; b.f = y;
  unsigned int ua = a.u + 0x8000u;
  unsigned int ub = b.u + 0x8000u;
  return __builtin_amdgcn_perm(ub, ua, 0x07060302u);
}

static __device__ __forceinline__ unsigned short f2bf(float x) {
  union { float f; unsigned int u; } a; a.f = x;
  return (unsigned short)((a.u + 0x8000u) >> 16);
}

// ---- Pass 1a: Wt[n][k] = bf16(W[k][n]), W = Wv_p (k<2048) else Wv_d ----
__global__ __launch_bounds__(256)
void prep_wt(const float* __restrict__ Wp, const float* __restrict__ Wd,
             unsigned short* __restrict__ Wt) {
  __shared__ float tile[32][33];
  const int k0 = blockIdx.x * 32;
  const int n0 = blockIdx.y * 32;
  const int tx = threadIdx.x;
  const int ty = threadIdx.y;
  const float* W = (k0 < 2048) ? Wp : Wd;
  const int kk0 = (k0 < 2048) ? k0 : k0 - 2048;
#pragma unroll
  for (int i = 0; i < 4; ++i) {
    int r = ty * 4 + i;
    tile[r][tx] = W[(size_t)(kk0 + r) * 2048 + n0 + tx];
  }
  __syncthreads();
#pragma unroll
  for (int i = 0; i < 4; ++i) {
    int r = ty * 4 + i;
    Wt[(size_t)(n0 + r) * (size_t)K_DIM + k0 + tx] = f2bf(tile[tx][r]);
  }
}

// ---- Pass 1b: Abf[m][k] = bf16([protein | drug][m][k]) ----
__global__ __launch_bounds__(256)
void cast_a(const float* __restrict__ P, const float* __restrict__ Dg,
            unsigned int* __restrict__ Abf) {
  int idx = blockIdx.x * 256 + threadIdx.x;
  int row = idx >> 10;
  int j = (idx & 1023) << 2;
  const float* src = (j < 2048) ? (P + (size_t)row * 2048 + j)
                                : (Dg + (size_t)row * 2048 + (j - 2048));
  float4v v = *(const float4v*)src;
  uint2v o;
  o.x = pack_bf16x2(v.x, v.y);
  o.y = pack_bf16x2(v.z, v.w);
  *(uint2v*)(Abf + (size_t)row * 2048 + (j >> 1)) = o;
}

#define VMW(N) asm volatile("s_waitcnt vmcnt(" #N ")" ::: "memory")
#define LGW0() asm volatile("s_waitcnt lgkmcnt(0)" ::: "memory")
#define BAR() __builtin_amdgcn_s_barrier()
#define SP1 __builtin_amdgcn_s_setprio(1);
#define SP0 __builtin_amdgcn_s_setprio(0);

__global__ __launch_bounds__(512, 1)
void gemm8(const unsigned short* __restrict__ Abf,
           const unsigned short* __restrict__ Wt,
           float* __restrict__ out) {
  __shared__ unsigned short As[2][256 * 64];  // 64 KB total (A only)

  const int t = threadIdx.x;
  const int w = t >> 6, l = t & 63;
  const int wm = w >> 2, wn = w & 3;          // 2x4 wave grid
  const int lr = l & 15, q16 = l >> 4, xr = lr & 7;

  // Chunked XCD swizzle: XCD (bx&7) owns contiguous logical [x*64,(x+1)*64)
  const int bx = blockIdx.x;                  // 512 blocks
  const int logical = (bx & 7) * 64 + (bx >> 3);
  const int tn = logical & 7, tm = logical >> 3;
  const int m0 = tm << 8, n0 = tn << 8;

  // A staging: row_in = t>>3, granule pos = t&7, swizzled src granule = pos^row
  const int srow = t >> 3;
  const int sk = (((t & 7) ^ (srow & 7)) << 3);

  auto stage_a = [&](int buf, int k0, int h) {
#pragma unroll
    for (int sub = 0; sub < 2; ++sub) {
      const int row = m0 + sub * 128 + h * 64 + srow;
      const unsigned short* g = Abf + (size_t)row * K_DIM + (k0 + sk);
      const int ldsrow0 = sub * 128 + h * 64 + (w << 3);
      __builtin_amdgcn_global_load_lds((gp_t)(const void*)g,
                                       (lp_t)&As[buf][ldsrow0 * 64], 16, 0, 0);
    }
  };

  float4v acc[8][4];
#pragma unroll
  for (int i = 0; i < 8; ++i)
#pragma unroll
    for (int j = 0; j < 4; ++j)
      acc[i][j] = (float4v){0.f, 0.f, 0.f, 0.f};

  const int aoff = (wm * 128 + lr) * 64;
  const int c0 = (q16 ^ xr) << 3;            // ks = 0 (swizzled granule)
  const int c1 = ((4 + q16) ^ xr) << 3;      // ks = 1

  // Per-thread B global base (constant): row = n0 + wn*64 + j*16 + lr,
  // in-row elem offset = (ks*4 + q16)*8. Only k1 varies per tile.
  const unsigned short* bBase[4];
#pragma unroll
  for (int j = 0; j < 4; ++j)
    bBase[j] = Wt + (size_t)(n0 + wn * 64 + j * 16 + lr) * (size_t)K_DIM +
               q16 * 8;

  // Full operand set for one tile: A 8 m-frags x 2 ks (LDS), B 4 x 2 (global).
  short8 aR[8][2];
  short8 bR[4][2];

  // ---- prologue ----
  stage_a(0, 0, 0);     // VMEM 1-2
  stage_a(0, 0, 1);     // 3-4
  stage_a(1, 64, 0);    // 5-6
  stage_a(1, 64, 1);    // 7-8
#pragma unroll
  for (int j = 0; j < 4; ++j) {               // B(0) direct: VMEM 9-16
    bR[j][0] = *(const short8*)&bBase[j][0];
    bR[j][1] = *(const short8*)&bBase[j][32];
  }
  VMW(8);               // retires VMEM 1-8 = S_A(0), S_A(1)
  BAR();
  {
    const unsigned short* Ac = &As[0][0];
#pragma unroll
    for (int i = 0; i < 8; ++i) {
      aR[i][0] = *(const short8*)&Ac[aoff + i * 1024 + c0];
      aR[i][1] = *(const short8*)&Ac[aoff + i * 1024 + c1];
    }
  }
  LGW0();               // seam fence (R8 lesson): every wave's aR(0) reads...
  BAR();                // ...drained before ANY wave stages S_A(2) into buf0

  // tile body: MFMA(t) on CUR regs; in-place refill aR<-AcN (LDS, tile t+1)
  // and bR<-global (tile t+1, k-offset kN).
  auto tile_mfma = [&](const unsigned short* AcN, int kN, bool doread) {
    SP1
#pragma unroll
    for (int ks = 0; ks < 2; ++ks) {
      const int cks = ks ? c1 : c0;
#pragma unroll
      for (int i = 0; i < 8; ++i) {
#pragma unroll
        for (int j = 0; j < 4; ++j)
          acc[i][j] = __builtin_amdgcn_mfma_f32_16x16x32_bf16(
              aR[i][ks], bR[j][ks], acc[i][j], 0, 0, 0);
        if (doread)
          aR[i][ks] = *(const short8*)&AcN[aoff + i * 1024 + cks];
      }
      if (doread) {
#pragma unroll
        for (int j = 0; j < 4; ++j)
          bR[j][ks] = *(const short8*)&bBase[j][kN + ks * 32];
      }
    }
    SP0
  };

  // ---- main loop: tiles 0..61, full body ----
  for (int tt = 0; tt < 62; ++tt) {
    const int buf = tt & 1;
    const int k2 = tt * 64 + 128;  // tile tt+2 (A stage)
    const int k1 = tt * 64 + 64;   // tile tt+1 (B refill)
    // stage S_A(tt+2) -> buf (all waves' R_A(tt) reads fenced by prior BAR)
    stage_a(buf, k2, 0);
    stage_a(buf, k2, 1);
    // MFMA(tt); refill aR<-As[buf^1] (t+1), bR<-global k1
    tile_mfma(&As[buf ^ 1][0], k1, true);
    VMW(8);   // retires the 4 S_A(tt+2) glls; B(t+1) loads stay in flight
    LGW0();   // drains this wave's R_A(tt+1) ds_reads
    BAR();
  }

  // ---- tile 62: MFMA(62) + refill R_A(63)<-buf1 (staged t=61, retired by
  //      t=61's VMW(8)+BAR) + B(63) global ----
  tile_mfma(&As[1][0], 4032, true);
  // ---- tile 63: MFMA only (compiler inserts lgkm/vmcnt waits for operands)
  tile_mfma(nullptr, 0, false);

  // ---- C write: col = lane&15, row = (lane>>4)*4 + reg; both output halves
  const int rbase = m0 + wm * 128 + q16 * 4;
  const int cbase = n0 + wn * 64 + lr;
#pragma unroll
  for (int f = 0; f < 8; ++f)
#pragma unroll
    for (int j = 0; j < 4; ++j) {
      const int row = rbase + f * 16;
      const int col = cbase + j * 16;
#pragma unroll
      for (int r = 0; r < 4; ++r) {
        float v = acc[f][j][r] * 0.5f;
        size_t o = (size_t)(row + r) * (size_t)OUT_LD + col;
        out[o] = v;
        out[o + N_DIM] = v;
      }
    }
}

// ---- mid fallback (ws holds Wt only): fp32-A m97-style GEMM ----
__global__ __launch_bounds__(256)
void gemm_k(const float* __restrict__ Ap, const float* __restrict__ Ad,
            const unsigned short* __restrict__ Wt,
            float* __restrict__ out) {
  __shared__ unsigned short As[128 * 64];
  __shared__ unsigned short Bsm[128 * 64];

  const int t = threadIdx.x;
  const int bx = blockIdx.x;
  const int tn = bx & 15, tm = bx >> 4;
  const int m0 = tm << 7, n0 = tn << 7;
  const int w = t >> 6, l = t & 63;
  const int wmm = w & 1, wnn = w >> 1;
  const int lr = l & 15, q = l >> 4;

  const int rB = t >> 3;
  const int kB = (t & 7) * 8;

  float4v acc[4][4];
#pragma unroll
  for (int i = 0; i < 4; ++i)
#pragma unroll
    for (int j = 0; j < 4; ++j)
      acc[i][j] = (float4v){0.f, 0.f, 0.f, 0.f};

  for (int k0 = 0; k0 < K_DIM; k0 += 64) {
#pragma unroll
    for (int i = 0; i < 4; ++i) {
      const unsigned short* g =
          Wt + (size_t)(n0 + i * 32 + rB) * (size_t)K_DIM + (k0 + kB);
      __builtin_amdgcn_global_load_lds((gp_t)(const void*)g,
                                       (lp_t)&Bsm[i * 2048 + w * 512], 16, 0, 0);
    }
    {
      const float* base;
      int kk;
      if (k0 < 2048) { base = Ap; kk = k0; } else { base = Ad; kk = k0 - 2048; }
      const int rA = t >> 4;
      const int cA = (t & 15) * 4;
#pragma unroll
      for (int i = 0; i < 8; ++i) {
        int m = i * 16 + rA;
        float4v v = *(const float4v*)(base + (size_t)(m0 + m) * 2048 + kk + cA);
        uint2v o;
        o.x = pack_bf16x2(v.x, v.y);
        o.y = pack_bf16x2(v.z, v.w);
        *(uint2v*)&As[m * 64 + cA] = o;
      }
    }
    __syncthreads();

#pragma unroll
    for (int ks = 0; ks < 2; ++ks) {
      short8 a2[4], b2[4];
#pragma unroll
      for (int i = 0; i < 4; ++i) {
        a2[i] = *(const short8*)&As[(wmm * 64 + i * 16 + lr) * 64 + ks * 32 + q * 8];
        b2[i] = *(const short8*)&Bsm[(wnn * 64 + i * 16 + lr) * 64 + ks * 32 + q * 8];
      }
#pragma unroll
      for (int i = 0; i < 4; ++i)
#pragma unroll
        for (int j = 0; j < 4; ++j)
          acc[i][j] = __builtin_amdgcn_mfma_f32_16x16x32_bf16(a2[i], b2[j],
                                                              acc[i][j], 0, 0, 0);
    }
    __syncthreads();
  }

#pragma unroll
  for (int i = 0; i < 4; ++i) {
    const int r0 = m0 + wmm * 64 + i * 16 + q * 4;
#pragma unroll
    for (int j = 0; j < 4; ++j) {
      const int c = n0 + wnn * 64 + j * 16 + lr;
#pragma unroll
      for (int r = 0; r < 4; ++r) {
        float v = acc[i][j][r] * 0.5f;
        size_t o = (size_t)(r0 + r) * (size_t)OUT_LD + c;
        out[o] = v;
        out[o + 2048] = v;
      }
    }
  }
}

// ---- insurance fallback (no usable ws): fp32 LDS-tiled vector GEMM ----
__global__ __launch_bounds__(256)
void gemm_fallback(const float* __restrict__ P, const float* __restrict__ Dg,
                   const float* __restrict__ Wp, const float* __restrict__ Wd,
                   float* __restrict__ out) {
  __shared__ float Asf[64][17];
  __shared__ float Bsf[16][65];
  const int bx = blockIdx.x;
  const int by = blockIdx.y;
  const int t = threadIdx.x;
  const int tc = t & 15, trw = t >> 4;
  const int m0 = by * 64, n0 = bx * 64;
  float accf[4][4] = {};
  for (int k0 = 0; k0 < 4096; k0 += 16) {
    const float* Asrc = (k0 < 2048) ? P : Dg;
    const float* Bsrc = (k0 < 2048) ? Wp : Wd;
    const int kk = k0 & 2047;
#pragma unroll
    for (int i = 0; i < 4; ++i) {
      int r = i * 16 + trw;
      Asf[r][tc] = Asrc[(size_t)(m0 + r) * 2048 + kk + tc];
    }
#pragma unroll
    for (int i = 0; i < 4; ++i) {
      int r = i * 4 + (t >> 6);
      int c = t & 63;
      Bsf[r][c] = Bsrc[(size_t)(kk + r) * 2048 + n0 + c];
    }
    __syncthreads();
#pragma unroll
    for (int k2 = 0; k2 < 16; ++k2) {
      float a[4], b[4];
#pragma unroll
      for (int i = 0; i < 4; ++i) a[i] = Asf[trw * 4 + i][k2];
#pragma unroll
      for (int j = 0; j < 4; ++j) b[j] = Bsf[k2][tc * 4 + j];
#pragma unroll
      for (int i = 0; i < 4; ++i)
#pragma unroll
        for (int j = 0; j < 4; ++j) accf[i][j] += a[i] * b[j];
    }
    __syncthreads();
  }
#pragma unroll
  for (int i = 0; i < 4; ++i)
#pragma unroll
    for (int j = 0; j < 4; ++j) {
      float v = accf[i][j] * 0.5f;
      size_t o = (size_t)(m0 + trw * 4 + i) * 4096 + n0 + tc * 4 + j;
      out[o] = v;
      out[o + 2048] = v;
    }
}

extern "C" void kernel_launch(void* const* d_in, const int* in_sizes, int n_in,
                              void* d_out, int out_size, void* d_ws, size_t ws_size,
                              hipStream_t stream) {
  // setup_inputs order: protein, drug, mask_prot, mask_drug,
  //                     Wq_p, Wk_p, Wv_p, Wq_d, Wk_d, Wv_d
  const float* protein = (const float*)d_in[0];
  const float* drug    = (const float*)d_in[1];
  const float* Wv_p    = (const float*)d_in[6];
  const float* Wv_d    = (const float*)d_in[9];
  float* out = (float*)d_out;

  const size_t wt_bytes = (size_t)N_DIM * K_DIM * sizeof(unsigned short);  // 16.8 MB
  const size_t a_bytes  = (size_t)M_DIM * K_DIM * sizeof(unsigned short);  // 134 MB

  if (ws_size >= wt_bytes) {
    unsigned short* Wt = (unsigned short*)d_ws;
    prep_wt<<<dim3(128, 64), dim3(32, 8), 0, stream>>>(Wv_p, Wv_d, Wt);
    if (ws_size >= wt_bytes + a_bytes) {
      unsigned int* Abf = (unsigned int*)((char*)d_ws + wt_bytes);
      cast_a<<<65536, 256, 0, stream>>>(protein, drug, Abf);
      gemm8<<<512, 512, 0, stream>>>((const unsigned short*)Abf, Wt, out);
    } else {
      gemm_k<<<2048, 256, 0, stream>>>(protein, drug, Wt, out);
    }
  } else {
    gemm_fallback<<<dim3(32, 256), 256, 0, stream>>>(protein, drug, Wv_p, Wv_d, out);
  }
}

// Round 11
// 754.502 us; speedup vs baseline: 1.1150x; 1.1150x over previous
//
#include <hip/hip_runtime.h>
#include <stdint.h>

// CAN_Layer reduces exactly to: out[:, :2048] = out[:, 2048:] =
//   0.5 * (protein @ Wv_p + drug @ Wv_d)
// (seq-len 1 -> softmax over singleton axis == 1 -> attention = identity on V).
//
// Pipeline:
//   Pass 1a: cast+transpose Wv_p/Wv_d -> Wt bf16 [2048][4096] (B^T layout).
//   Pass 1b: cast protein|drug -> Abf bf16 [16384][4096].
//   Pass 2:  gemm8 — 256x256 tile, BK=64, 8 waves (2x4), ONE sync point per
//            K-tile: 64 MFMA(t) interleaved with 24 ds_reads R(t+1) that
//            refill IN-PLACE the registers MFMA(t) just consumed.
//
// This is the R8 kernel, restored verbatim. It is the verified optimum of
// the explored design space (303us gemm, MfmaUtil 39.5%, 0 bank conflicts):
//   R2 quadrant/per-phase-vmcnt 369 | R3 +1-vmcnt/tile 373 | R4/R5
//   read-ahead phases 421/427 | R9 m201 fine cadence 335 | R10 B-from-
//   global 390. Five neighborhoods around R8 all regress; 908 TF-equiv =
//   the documented plain-HIP ~900 TF structural plateau.
//
// Sync design (the part that makes the weave race-free):
//   body(t): stage S(t+2)->buf b (8 gll) | 64 MFMA(t) on CUR regs,
//            in-place refill R(t+1)<-buf nb woven between MFMA groups |
//            VMW(0) LGW0 BAR.
//   A region is overwritten only after a barrier whose entry required EVERY
//   wave to drain its reads (per-wave LGW0 before each BAR); staged data is
//   read only after a barrier whose entry required every wave's VMW(0).
//   Prologue seam (R8's fix over R7): LGW0+BAR after the R(0) reads so no
//   wave stages S(2) over another wave's pending prologue reads.

typedef __attribute__((ext_vector_type(8))) short short8;
typedef __attribute__((ext_vector_type(4))) float float4v;
typedef __attribute__((ext_vector_type(2))) unsigned int uint2v;

typedef const __attribute__((address_space(1))) unsigned int* gp_t;
typedef __attribute__((address_space(3))) unsigned int* lp_t;

#define M_DIM 16384
#define N_DIM 2048
#define K_DIM 4096
#define OUT_LD 4096

static __device__ __forceinline__ unsigned int pack_bf16x2(float x, float y) {
  union { float f; unsigned int u; } a, b;
  a.f = x; b.f = y;
  unsigned int ua = a.u + 0x8000u;
  unsigned int ub = b.u + 0x8000u;
  return __builtin_amdgcn_perm(ub, ua, 0x07060302u);
}

static __device__ __forceinline__ unsigned short f2bf(float x) {
  union { float f; unsigned int u; } a; a.f = x;
  return (unsigned short)((a.u + 0x8000u) >> 16);
}

// ---- Pass 1a: Wt[n][k] = bf16(W[k][n]), W = Wv_p (k<2048) else Wv_d ----
__global__ __launch_bounds__(256)
void prep_wt(const float* __restrict__ Wp, const float* __restrict__ Wd,
             unsigned short* __restrict__ Wt) {
  __shared__ float tile[32][33];
  const int k0 = blockIdx.x * 32;
  const int n0 = blockIdx.y * 32;
  const int tx = threadIdx.x;
  const int ty = threadIdx.y;
  const float* W = (k0 < 2048) ? Wp : Wd;
  const int kk0 = (k0 < 2048) ? k0 : k0 - 2048;
#pragma unroll
  for (int i = 0; i < 4; ++i) {
    int r = ty * 4 + i;
    tile[r][tx] = W[(size_t)(kk0 + r) * 2048 + n0 + tx];
  }
  __syncthreads();
#pragma unroll
  for (int i = 0; i < 4; ++i) {
    int r = ty * 4 + i;
    Wt[(size_t)(n0 + r) * (size_t)K_DIM + k0 + tx] = f2bf(tile[tx][r]);
  }
}

// ---- Pass 1b: Abf[m][k] = bf16([protein | drug][m][k]) ----
__global__ __launch_bounds__(256)
void cast_a(const float* __restrict__ P, const float* __restrict__ Dg,
            unsigned int* __restrict__ Abf) {
  int idx = blockIdx.x * 256 + threadIdx.x;
  int row = idx >> 10;
  int j = (idx & 1023) << 2;
  const float* src = (j < 2048) ? (P + (size_t)row * 2048 + j)
                                : (Dg + (size_t)row * 2048 + (j - 2048));
  float4v v = *(const float4v*)src;
  uint2v o;
  o.x = pack_bf16x2(v.x, v.y);
  o.y = pack_bf16x2(v.z, v.w);
  *(uint2v*)(Abf + (size_t)row * 2048 + (j >> 1)) = o;
}

#define VMW(N) asm volatile("s_waitcnt vmcnt(" #N ")" ::: "memory")
#define LGW0() asm volatile("s_waitcnt lgkmcnt(0)" ::: "memory")
#define BAR() __builtin_amdgcn_s_barrier()
#define SP1 __builtin_amdgcn_s_setprio(1);
#define SP0 __builtin_amdgcn_s_setprio(0);

__global__ __launch_bounds__(512, 1)
void gemm8(const unsigned short* __restrict__ Abf,
           const unsigned short* __restrict__ Wt,
           float* __restrict__ out) {
  __shared__ unsigned short As[2][256 * 64];  // 64 KB
  __shared__ unsigned short Bs[2][256 * 64];  // 64 KB

  const int t = threadIdx.x;
  const int w = t >> 6, l = t & 63;
  const int wm = w >> 2, wn = w & 3;          // 2x4 wave grid
  const int lr = l & 15, q16 = l >> 4, xr = lr & 7;

  // Chunked XCD swizzle: XCD (bx&7) owns contiguous logical [x*64,(x+1)*64)
  const int bx = blockIdx.x;                  // 512 blocks
  const int logical = (bx & 7) * 64 + (bx >> 3);
  const int tn = logical & 7, tm = logical >> 3;
  const int m0 = tm << 8, n0 = tn << 8;

  // staging: row_in = t>>3, granule pos = t&7, swizzled src granule = pos^row
  const int srow = t >> 3;
  const int sk = (((t & 7) ^ (srow & 7)) << 3);
  const int brr = srow & 31;
  const int bsel = t >> 8;

  auto stage_a = [&](int buf, int k0, int h) {
#pragma unroll
    for (int sub = 0; sub < 2; ++sub) {
      const int row = m0 + sub * 128 + h * 64 + srow;
      const unsigned short* g = Abf + (size_t)row * K_DIM + (k0 + sk);
      const int ldsrow0 = sub * 128 + h * 64 + (w << 3);
      __builtin_amdgcn_global_load_lds((gp_t)(const void*)g,
                                       (lp_t)&As[buf][ldsrow0 * 64], 16, 0, 0);
    }
  };
  auto stage_b = [&](int buf, int k0, int nh) {
#pragma unroll
    for (int sub = 0; sub < 2; ++sub) {
      const int wnr = sub * 2 + bsel;
      const int ncol = n0 + wnr * 64 + nh * 32 + brr;
      const unsigned short* g = Wt + (size_t)ncol * K_DIM + (k0 + sk);
      const int ldsrow0 = wnr * 64 + nh * 32 + ((w & 3) << 3);
      __builtin_amdgcn_global_load_lds((gp_t)(const void*)g,
                                       (lp_t)&Bs[buf][ldsrow0 * 64], 16, 0, 0);
    }
  };

  float4v acc[8][4];
#pragma unroll
  for (int i = 0; i < 8; ++i)
#pragma unroll
    for (int j = 0; j < 4; ++j)
      acc[i][j] = (float4v){0.f, 0.f, 0.f, 0.f};

  const int aoff = (wm * 128 + lr) * 64;
  const int boff = (wn * 64 + lr) * 64;
  const int c0 = (q16 ^ xr) << 3;            // ks = 0 (swizzled granule)
  const int c1 = ((4 + q16) ^ xr) << 3;      // ks = 1

  // Full operand set for one tile: A 8 m-frags x 2 ks, B 4 n-frags x 2 ks.
  short8 aR[8][2];
  short8 bR[4][2];

  // ---- prologue: stage tiles 0,1; confirm tile 0; read R(0); fence ----
  stage_a(0, 0, 0);
  stage_a(0, 0, 1);
  stage_b(0, 0, 0);
  stage_b(0, 0, 1);
  stage_a(1, 64, 0);
  stage_b(1, 64, 0);
  stage_b(1, 64, 1);
  stage_a(1, 64, 1);
  VMW(8);                 // retires tile 0's 8, keeps tile 1's 8
  BAR();
  {
    const unsigned short* Ac = &As[0][0];
    const unsigned short* Bc = &Bs[0][0];
#pragma unroll
    for (int i = 0; i < 8; ++i) {
      aR[i][0] = *(const short8*)&Ac[aoff + i * 1024 + c0];
      aR[i][1] = *(const short8*)&Ac[aoff + i * 1024 + c1];
    }
#pragma unroll
    for (int j = 0; j < 4; ++j) {
      bR[j][0] = *(const short8*)&Bc[boff + j * 1024 + c0];
      bR[j][1] = *(const short8*)&Bc[boff + j * 1024 + c1];
    }
  }
  LGW0();                 // seam fence: every wave's R(0) reads drained...
  BAR();                  // ...before ANY wave may stage S(2) into buf0

  // tile body: MFMA(t) on CUR regs, in-place refill from AcN/BcN (tile t+1)
  auto tile_mfma = [&](const unsigned short* AcN, const unsigned short* BcN,
                       bool doread) {
    SP1
#pragma unroll
    for (int ks = 0; ks < 2; ++ks) {
      const int cks = ks ? c1 : c0;
#pragma unroll
      for (int i = 0; i < 8; ++i) {
#pragma unroll
        for (int j = 0; j < 4; ++j)
          acc[i][j] = __builtin_amdgcn_mfma_f32_16x16x32_bf16(
              aR[i][ks], bR[j][ks], acc[i][j], 0, 0, 0);
        if (doread)
          aR[i][ks] = *(const short8*)&AcN[aoff + i * 1024 + cks];
      }
      if (doread) {
#pragma unroll
        for (int j = 0; j < 4; ++j)
          bR[j][ks] = *(const short8*)&BcN[boff + j * 1024 + cks];
      }
    }
    SP0
  };

  // ---- main loop: tiles 0..61, full body ----
  for (int tt = 0; tt < 62; ++tt) {
    const int buf = tt & 1;
    const int k2 = tt * 64 + 128;  // tile tt+2
    // stage S(tt+2) -> buf (safe: all waves' R(tt) reads fenced by prior BAR)
    stage_a(buf, k2, 0);
    stage_a(buf, k2, 1);
    stage_b(buf, k2, 0);
    stage_b(buf, k2, 1);
    // MFMA(tt) with woven in-place refill R(tt+1) from buf^1
    tile_mfma(&As[buf ^ 1][0], &Bs[buf ^ 1][0], true);
    VMW(0);   // drains S(tt+2) (issued ~2400cyc ago) + anything older
    LGW0();   // drains this wave's R(tt+1) reads
    BAR();    // publishes both; no wave proceeds until all drained
  }

  // ---- t=62: MFMA(62) + read R(63) from buf1 (staged t=61, drained+BAR'd)
  tile_mfma(&As[1][0], &Bs[1][0], true);
  // ---- t=63: MFMA only (no further LDS activity; compiler orders lgkm)
  tile_mfma(nullptr, nullptr, false);

  // ---- C write: col = lane&15, row = (lane>>4)*4 + reg; both output halves
  const int rbase = m0 + wm * 128 + q16 * 4;
  const int cbase = n0 + wn * 64 + lr;
#pragma unroll
  for (int f = 0; f < 8; ++f)
#pragma unroll
    for (int j = 0; j < 4; ++j) {
      const int row = rbase + f * 16;
      const int col = cbase + j * 16;
#pragma unroll
      for (int r = 0; r < 4; ++r) {
        float v = acc[f][j][r] * 0.5f;
        size_t o = (size_t)(row + r) * (size_t)OUT_LD + col;
        out[o] = v;
        out[o + N_DIM] = v;
      }
    }
}

// ---- mid fallback (ws holds Wt only): fp32-A m97-style GEMM ----
__global__ __launch_bounds__(256)
void gemm_k(const float* __restrict__ Ap, const float* __restrict__ Ad,
            const unsigned short* __restrict__ Wt,
            float* __restrict__ out) {
  __shared__ unsigned short As[128 * 64];
  __shared__ unsigned short Bsm[128 * 64];

  const int t = threadIdx.x;
  const int bx = blockIdx.x;
  const int tn = bx & 15, tm = bx >> 4;
  const int m0 = tm << 7, n0 = tn << 7;
  const int w = t >> 6, l = t & 63;
  const int wmm = w & 1, wnn = w >> 1;
  const int lr = l & 15, q = l >> 4;

  const int rB = t >> 3;
  const int kB = (t & 7) * 8;

  float4v acc[4][4];
#pragma unroll
  for (int i = 0; i < 4; ++i)
#pragma unroll
    for (int j = 0; j < 4; ++j)
      acc[i][j] = (float4v){0.f, 0.f, 0.f, 0.f};

  for (int k0 = 0; k0 < K_DIM; k0 += 64) {
#pragma unroll
    for (int i = 0; i < 4; ++i) {
      const unsigned short* g =
          Wt + (size_t)(n0 + i * 32 + rB) * (size_t)K_DIM + (k0 + kB);
      __builtin_amdgcn_global_load_lds((gp_t)(const void*)g,
                                       (lp_t)&Bsm[i * 2048 + w * 512], 16, 0, 0);
    }
    {
      const float* base;
      int kk;
      if (k0 < 2048) { base = Ap; kk = k0; } else { base = Ad; kk = k0 - 2048; }
      const int rA = t >> 4;
      const int cA = (t & 15) * 4;
#pragma unroll
      for (int i = 0; i < 8; ++i) {
        int m = i * 16 + rA;
        float4v v = *(const float4v*)(base + (size_t)(m0 + m) * 2048 + kk + cA);
        uint2v o;
        o.x = pack_bf16x2(v.x, v.y);
        o.y = pack_bf16x2(v.z, v.w);
        *(uint2v*)&As[m * 64 + cA] = o;
      }
    }
    __syncthreads();

#pragma unroll
    for (int ks = 0; ks < 2; ++ks) {
      short8 a2[4], b2[4];
#pragma unroll
      for (int i = 0; i < 4; ++i) {
        a2[i] = *(const short8*)&As[(wmm * 64 + i * 16 + lr) * 64 + ks * 32 + q * 8];
        b2[i] = *(const short8*)&Bsm[(wnn * 64 + i * 16 + lr) * 64 + ks * 32 + q * 8];
      }
#pragma unroll
      for (int i = 0; i < 4; ++i)
#pragma unroll
        for (int j = 0; j < 4; ++j)
          acc[i][j] = __builtin_amdgcn_mfma_f32_16x16x32_bf16(a2[i], b2[j],
                                                              acc[i][j], 0, 0, 0);
    }
    __syncthreads();
  }

#pragma unroll
  for (int i = 0; i < 4; ++i) {
    const int r0 = m0 + wmm * 64 + i * 16 + q * 4;
#pragma unroll
    for (int j = 0; j < 4; ++j) {
      const int c = n0 + wnn * 64 + j * 16 + lr;
#pragma unroll
      for (int r = 0; r < 4; ++r) {
        float v = acc[i][j][r] * 0.5f;
        size_t o = (size_t)(r0 + r) * (size_t)OUT_LD + c;
        out[o] = v;
        out[o + 2048] = v;
      }
    }
  }
}

// ---- insurance fallback (no usable ws): fp32 LDS-tiled vector GEMM ----
__global__ __launch_bounds__(256)
void gemm_fallback(const float* __restrict__ P, const float* __restrict__ Dg,
                   const float* __restrict__ Wp, const float* __restrict__ Wd,
                   float* __restrict__ out) {
  __shared__ float Asf[64][17];
  __shared__ float Bsf[16][65];
  const int bx = blockIdx.x;
  const int by = blockIdx.y;
  const int t = threadIdx.x;
  const int tc = t & 15, trw = t >> 4;
  const int m0 = by * 64, n0 = bx * 64;
  float accf[4][4] = {};
  for (int k0 = 0; k0 < 4096; k0 += 16) {
    const float* Asrc = (k0 < 2048) ? P : Dg;
    const float* Bsrc = (k0 < 2048) ? Wp : Wd;
    const int kk = k0 & 2047;
#pragma unroll
    for (int i = 0; i < 4; ++i) {
      int r = i * 16 + trw;
      Asf[r][tc] = Asrc[(size_t)(m0 + r) * 2048 + kk + tc];
    }
#pragma unroll
    for (int i = 0; i < 4; ++i) {
      int r = i * 4 + (t >> 6);
      int c = t & 63;
      Bsf[r][c] = Bsrc[(size_t)(kk + r) * 2048 + n0 + c];
    }
    __syncthreads();
#pragma unroll
    for (int k2 = 0; k2 < 16; ++k2) {
      float a[4], b[4];
#pragma unroll
      for (int i = 0; i < 4; ++i) a[i] = Asf[trw * 4 + i][k2];
#pragma unroll
      for (int j = 0; j < 4; ++j) b[j] = Bsf[k2][tc * 4 + j];
#pragma unroll
      for (int i = 0; i < 4; ++i)
#pragma unroll
        for (int j = 0; j < 4; ++j) accf[i][j] += a[i] * b[j];
    }
    __syncthreads();
  }
#pragma unroll
  for (int i = 0; i < 4; ++i)
#pragma unroll
    for (int j = 0; j < 4; ++j) {
      float v = accf[i][j] * 0.5f;
      size_t o = (size_t)(m0 + trw * 4 + i) * 4096 + n0 + tc * 4 + j;
      out[o] = v;
      out[o + 2048] = v;
    }
}

extern "C" void kernel_launch(void* const* d_in, const int* in_sizes, int n_in,
                              void* d_out, int out_size, void* d_ws, size_t ws_size,
                              hipStream_t stream) {
  // setup_inputs order: protein, drug, mask_prot, mask_drug,
  //                     Wq_p, Wk_p, Wv_p, Wq_d, Wk_d, Wv_d
  const float* protein = (const float*)d_in[0];
  const float* drug    = (const float*)d_in[1];
  const float* Wv_p    = (const float*)d_in[6];
  const float* Wv_d    = (const float*)d_in[9];
  float* out = (float*)d_out;

  const size_t wt_bytes = (size_t)N_DIM * K_DIM * sizeof(unsigned short);  // 16.8 MB
  const size_t a_bytes  = (size_t)M_DIM * K_DIM * sizeof(unsigned short);  // 134 MB

  if (ws_size >= wt_bytes) {
    unsigned short* Wt = (unsigned short*)d_ws;
    prep_wt<<<dim3(128, 64), dim3(32, 8), 0, stream>>>(Wv_p, Wv_d, Wt);
    if (ws_size >= wt_bytes + a_bytes) {
      unsigned int* Abf = (unsigned int*)((char*)d_ws + wt_bytes);
      cast_a<<<65536, 256, 0, stream>>>(protein, drug, Abf);
      gemm8<<<512, 512, 0, stream>>>((const unsigned short*)Abf, Wt, out);
    } else {
      gemm_k<<<2048, 256, 0, stream>>>(protein, drug, Wt, out);
    }
  } else {
    gemm_fallback<<<dim3(32, 256), 256, 0, stream>>>(protein, drug, Wv_p, Wv_d, out);
  }
}